// Round 8
// baseline (164.062 us; speedup 1.0000x reference)
//
#include <hip/hip_runtime.h>

// VQ-VAE vector quantizer. Round 8.
// z: [16,64,32,32] f32, emb: [8192,64] f32. N=16384 pts, C=64, V=8192.
// out = [ z_q_st (1048576) | idx as f32 (16384) | vq_loss (1) ]
//
// R7 post-mortem: k1 = 50us, VALUBusy 51%, 2 waves/SIMD, pt=2 -> load->MFMA->
// epilogue latency uncovered. VALU floor = 5 ops/score ~ 8.5us; B-ingest
// 512MB/L1 ~ 13us.
// R8: pt=4 (wave owns 64 points): B-ingest halves to 256MB, 4 independent
// MFMA+epilogue chains per tile hide latency. launch_bounds(256,2) -> VGPR
// cap 256 (~130 used, no spill).

typedef _Float16 half8 __attribute__((ext_vector_type(8)));
typedef float f32x4 __attribute__((ext_vector_type(4)));

#define N_PTS 16384
#define SPLITS 8
#define THR 0.08f

// e16 swizzled (halfs): off(v,c) = (v>>4)*1024 + (c>>5)*512
//                                   + ((c>>3)&3)*128 + (v&15)*8 + (c&7)
// -> per-wave B-frag load (tile T, half H): e16 + T*1024 + H*512 + lane*8,
//    contiguous 1KB, giving B[n=lane&15][k=(lane>>4)*8+j].

// ---------------- k_pre: emb -> swizzled fp16 + fp32 transpose, norms --------
__global__ __launch_bounds__(256) void k_pre(const float* __restrict__ emb,
                                             float* __restrict__ h,
                                             unsigned short* __restrict__ e16,
                                             float* __restrict__ embT,
                                             int* __restrict__ cnt) {
  int v = blockIdx.x * 256 + threadIdx.x;   // grid 32 -> 8192
  const float4* e4 = (const float4*)(emb + v * 64);
  float s = 0.f;
  float row[64];
#pragma unroll
  for (int i = 0; i < 16; ++i) {
    float4 a = e4[i];
    row[i * 4 + 0] = a.x; row[i * 4 + 1] = a.y;
    row[i * 4 + 2] = a.z; row[i * 4 + 3] = a.w;
    s += a.x * a.x + a.y * a.y + a.z * a.z + a.w * a.w;
  }
  unsigned short* base = e16 + (v >> 4) * 1024 + (v & 15) * 8;
#pragma unroll
  for (int c8 = 0; c8 < 8; ++c8) {
    half8 o;
#pragma unroll
    for (int j = 0; j < 8; ++j) o[j] = (_Float16)row[c8 * 8 + j];
    *(half8*)(base + (c8 >> 2) * 512 + (c8 & 3) * 128) = o;
  }
  // fp32 transpose: embT[c][v]; consecutive lanes -> consecutive v: coalesced
#pragma unroll
  for (int c = 0; c < 64; ++c) embT[c * 8192 + v] = row[c];
  h[v] = 0.5f * s;
  if (v == 0) *cnt = 0;
}

// ---------------- k1: 16x16x32 MFMA scores, 4 point-tiles per wave ----------
// grid (64, 8). block 256 = 4 waves; wave owns 64 points (4 tiles of 16),
// sweeps 1024 codes (64 tiles). B-frags loaded once per code-tile, used for
// 4 point-tiles -> B ingest 256MB total; 4 independent chains per tile.
__global__ __launch_bounds__(256, 2) void k1_score(
    const float* __restrict__ z, const unsigned short* __restrict__ e16,
    const float* __restrict__ h,
    float* __restrict__ ps, float* __restrict__ pi, float* __restrict__ p2) {
  const int tid = threadIdx.x;
  const int lane = tid & 63;
  const int wid = tid >> 6;
  const int cl = lane & 15;     // A row (point) / B col (code) within tile
  const int gq = lane >> 4;     // quad: selects k-slice / C rows
  const int n0 = blockIdx.x * 256 + wid * 64;
  const int split = blockIdx.y;

  const int b = n0 >> 10;
  const int hw0 = n0 & 1023;

  // A frags: A[pt][H]  with A[m=cl][k=gq*8+j], half H = channels H*32..+31
  half8 A[4][2];
  {
    const float* zb = z + b * 65536 + hw0 + cl;
#pragma unroll
    for (int pt = 0; pt < 4; ++pt)
#pragma unroll
      for (int H = 0; H < 2; ++H) {
        half8 a;
#pragma unroll
        for (int j = 0; j < 8; ++j)
          a[j] = (_Float16)zb[pt * 16 + (H * 32 + gq * 8 + j) * 1024];
        A[pt][H] = a;
      }
  }

  float s1[4][4], i1f[4][4], s2[4][4];
#pragma unroll
  for (int pt = 0; pt < 4; ++pt)
#pragma unroll
    for (int r = 0; r < 4; ++r) {
      s1[pt][r] = -3.0e38f; i1f[pt][r] = 0.f; s2[pt][r] = -3.0e38f;
    }

  const int vbase = split * 1024;
  const unsigned short* bbase = e16 + vbase * 64 + lane * 8;

#pragma unroll 2
  for (int T = 0; T < 64; ++T) {
    const unsigned short* bp = bbase + T * 1024;
    half8 B0 = *(const half8*)bp;
    half8 B1 = *(const half8*)(bp + 512);
    const int code = vbase + T * 16 + cl;
    const float nhv = -h[code];
    const float vf = (float)code;

#pragma unroll
    for (int pt = 0; pt < 4; ++pt) {
      f32x4 acc;
      acc[0] = nhv; acc[1] = nhv; acc[2] = nhv; acc[3] = nhv;
      acc = __builtin_amdgcn_mfma_f32_16x16x32_f16(A[pt][0], B0, acc, 0, 0, 0);
      acc = __builtin_amdgcn_mfma_f32_16x16x32_f16(A[pt][1], B1, acc, 0, 0, 0);

      // per-lane running top-2 for 4 rows (points), this lane's col (code)
#pragma unroll
      for (int r = 0; r < 4; ++r) {
        float sc = acc[r];
        s2[pt][r] = fmaxf(fminf(sc, s1[pt][r]), s2[pt][r]);
        bool gt = sc > s1[pt][r];               // strict: first occurrence
        i1f[pt][r] = gt ? vf : i1f[pt][r];
        s1[pt][r] = fmaxf(s1[pt][r], sc);
      }
    }
  }

  // butterfly merge across the 16 cols (lanes with same gq hold same rows)
#pragma unroll
  for (int off = 8; off >= 1; off >>= 1) {
#pragma unroll
    for (int pt = 0; pt < 4; ++pt)
#pragma unroll
      for (int r = 0; r < 4; ++r) {
        float os = __shfl_xor(s1[pt][r], off);
        float oi = __shfl_xor(i1f[pt][r], off);
        float o2 = __shfl_xor(s2[pt][r], off);
        s2[pt][r] = fmaxf(fmaxf(s2[pt][r], o2), fminf(s1[pt][r], os));
        bool gt = os > s1[pt][r];   // exact ties -> margin 0 -> rescue
        i1f[pt][r] = gt ? oi : i1f[pt][r];
        s1[pt][r] = fmaxf(s1[pt][r], os);
      }
  }

  if (cl == 0) {
#pragma unroll
    for (int pt = 0; pt < 4; ++pt)
#pragma unroll
      for (int r = 0; r < 4; ++r) {
        int n = n0 + pt * 16 + gq * 4 + r;     // C row = gq*4 + reg
        int o = split * N_PTS + n;
        ps[o] = s1[pt][r]; pi[o] = i1f[pt][r]; p2[o] = s2[pt][r];
      }
  }
}

// ---------------- k2: merge splits, margin test, emit idx ----------------
__global__ __launch_bounds__(256) void k2_merge(
    const float* __restrict__ ps, const float* __restrict__ pi,
    const float* __restrict__ p2,
    int* __restrict__ idxf, float* __restrict__ out_idx,
    int* __restrict__ list, int* __restrict__ cnt) {
  int n = blockIdx.x * 256 + threadIdx.x;   // grid 64 -> 16384
  float S1 = ps[n], I1 = pi[n], S2 = p2[n];
#pragma unroll
  for (int s = 1; s < SPLITS; ++s) {
    int o = s * N_PTS + n;
    float a = ps[o], ai = pi[o], a2 = p2[o];
    if (a > S1) { S2 = fmaxf(fmaxf(S2, a2), S1); S1 = a; I1 = ai; }
    else        { S2 = fmaxf(S2, a); }
  }
  idxf[n] = (int)I1;
  out_idx[n] = I1;
  if (S1 - S2 < THR) {
    int p = atomicAdd(cnt, 1);
    list[p] = n;
  }
}

// ---------------- k_rescue: exact fp32, 4 points/block, private codes --------
// Thread t owns 32 codes (8 float4 of embT); 4 points share the sweep.
// d[32 codes][4 pts] = 128 VGPR accumulators; z via broadcast LDS reads.
// No cross-lane ops in the hot loop.
__global__ __launch_bounds__(256, 1) void k_rescue(
    const float* __restrict__ z, const float* __restrict__ embT,
    const float* __restrict__ h, const int* __restrict__ list,
    const int* __restrict__ cnt,
    int* __restrict__ idxf, float* __restrict__ out_idx) {
  __shared__ float zsT[64][4];
  __shared__ int pn[4];
  __shared__ float rs[4][4], ri[4][4];
  const int tid = threadIdx.x;
  const int lane = tid & 63, wv = tid >> 6;
  const int count = *cnt;

  for (int base = blockIdx.x * 4; base < count; base += gridDim.x * 4) {
    const int P = min(4, count - base);
    __syncthreads();
    if (tid < 4) pn[tid] = list[base + min(tid, P - 1)];  // pad with last valid
    __syncthreads();
    {
      int p = tid >> 6, c = tid & 63;
      int n = pn[p];
      zsT[c][p] = z[(n >> 10) * 65536 + c * 1024 + (n & 1023)];
    }
    __syncthreads();

    float d[128];
#pragma unroll
    for (int i = 0; i < 128; ++i) d[i] = 0.f;

    const float4* eT = (const float4*)embT;   // [c][2048] float4 units
    for (int c = 0; c < 64; ++c) {
      float4 zp = *(const float4*)&zsT[c][0];     // broadcast, conflict-free
      const float4* rowp = eT + c * 2048 + tid;
#pragma unroll
      for (int s = 0; s < 8; ++s) {
        float4 ev = rowp[s * 256];
        float* dp = d + s * 16;
        dp[0]  = fmaf(ev.x, zp.x, dp[0]);  dp[1]  = fmaf(ev.x, zp.y, dp[1]);
        dp[2]  = fmaf(ev.x, zp.z, dp[2]);  dp[3]  = fmaf(ev.x, zp.w, dp[3]);
        dp[4]  = fmaf(ev.y, zp.x, dp[4]);  dp[5]  = fmaf(ev.y, zp.y, dp[5]);
        dp[6]  = fmaf(ev.y, zp.z, dp[6]);  dp[7]  = fmaf(ev.y, zp.w, dp[7]);
        dp[8]  = fmaf(ev.z, zp.x, dp[8]);  dp[9]  = fmaf(ev.z, zp.y, dp[9]);
        dp[10] = fmaf(ev.z, zp.z, dp[10]); dp[11] = fmaf(ev.z, zp.w, dp[11]);
        dp[12] = fmaf(ev.w, zp.x, dp[12]); dp[13] = fmaf(ev.w, zp.y, dp[13]);
        dp[14] = fmaf(ev.w, zp.z, dp[14]); dp[15] = fmaf(ev.w, zp.w, dp[15]);
      }
    }

    // per-thread argmax per point over its 32 codes (code-ascending, strict >)
    float bs[4], bi[4];
#pragma unroll
    for (int p = 0; p < 4; ++p) { bs[p] = -3.0e38f; bi[p] = 0.f; }
#pragma unroll
    for (int s = 0; s < 8; ++s) {
      float4 hv = *(const float4*)(h + s * 1024 + tid * 4);
#pragma unroll
      for (int k = 0; k < 4; ++k) {
        float hk = (k == 0) ? hv.x : (k == 1) ? hv.y : (k == 2) ? hv.z : hv.w;
        float cf = (float)(s * 1024 + tid * 4 + k);
#pragma unroll
        for (int p = 0; p < 4; ++p) {
          float sc = d[s * 16 + k * 4 + p] - hk;
          if (sc > bs[p]) { bs[p] = sc; bi[p] = cf; }
        }
      }
    }

    // wave butterfly (disjoint code sets; tie -> lower code), then cross-wave
#pragma unroll
    for (int off = 32; off >= 1; off >>= 1) {
#pragma unroll
      for (int p = 0; p < 4; ++p) {
        float os = __shfl_xor(bs[p], off);
        float oi = __shfl_xor(bi[p], off);
        if (os > bs[p] || (os == bs[p] && oi < bi[p])) { bs[p] = os; bi[p] = oi; }
      }
    }
    if (lane == 0)
#pragma unroll
      for (int p = 0; p < 4; ++p) { rs[wv][p] = bs[p]; ri[wv][p] = bi[p]; }
    __syncthreads();
    if (tid < 4) {
      int p = tid;
      float s = rs[0][p], i = ri[0][p];
#pragma unroll
      for (int w = 1; w < 4; ++w) {
        if (rs[w][p] > s || (rs[w][p] == s && ri[w][p] < i)) { s = rs[w][p]; i = ri[w][p]; }
      }
      if (p < P) {
        int n = pn[p];
        idxf[n] = (int)i;
        out_idx[n] = i;
      }
    }
  }
}

// ---------------- k3: gather, straight-through out, block partial loss --------
__global__ __launch_bounds__(256) void k3_quant(
    const float* __restrict__ z, const float* __restrict__ emb,
    const int* __restrict__ idxf,
    float* __restrict__ out, float* __restrict__ psum) {
  int t = blockIdx.x * 256 + threadIdx.x;   // grid 1024 -> 262144 float4 slots
  int g = t * 4;
  int b = g >> 16;
  int c = (g >> 10) & 63;
  int hw = g & 1023;
  int n = (b << 10) | hw;                   // n..n+3, 4-aligned
  float4 zv = *(const float4*)(z + g);
  int4 iv = *(const int4*)(idxf + n);
  float q0 = emb[iv.x * 64 + c];
  float q1 = emb[iv.y * 64 + c];
  float q2 = emb[iv.z * 64 + c];
  float q3 = emb[iv.w * 64 + c];
  float d0 = q0 - zv.x, d1 = q1 - zv.y, d2 = q2 - zv.z, d3 = q3 - zv.w;
  float4 o;
  o.x = zv.x + d0; o.y = zv.y + d1; o.z = zv.z + d2; o.w = zv.w + d3;
  *(float4*)(out + g) = o;
  float val = d0 * d0 + d1 * d1 + d2 * d2 + d3 * d3;
#pragma unroll
  for (int off = 32; off >= 1; off >>= 1) val += __shfl_down(val, off);
  __shared__ float wsum[4];
  int lane = threadIdx.x & 63, wv = threadIdx.x >> 6;
  if (lane == 0) wsum[wv] = val;
  __syncthreads();
  if (threadIdx.x == 0)
    psum[blockIdx.x] = wsum[0] + wsum[1] + wsum[2] + wsum[3];
}

// ---------------- k4: final loss reduce (1024 partials) ----------------
__global__ __launch_bounds__(256) void k4_loss(const float* __restrict__ psum,
                                               float* __restrict__ out_loss) {
  int tid = threadIdx.x;
  float val = psum[tid] + psum[tid + 256] + psum[tid + 512] + psum[tid + 768];
#pragma unroll
  for (int off = 32; off >= 1; off >>= 1) val += __shfl_down(val, off);
  __shared__ float wsum[4];
  int lane = tid & 63, wv = tid >> 6;
  if (lane == 0) wsum[wv] = val;
  __syncthreads();
  if (tid == 0)
    out_loss[0] = 1.25f * (wsum[0] + wsum[1] + wsum[2] + wsum[3]) * (1.0f / 1048576.0f);
}

extern "C" void kernel_launch(void* const* d_in, const int* in_sizes, int n_in,
                              void* d_out, int out_size, void* d_ws, size_t ws_size,
                              hipStream_t stream) {
  const float* z   = (const float*)d_in[0];
  const float* emb = (const float*)d_in[1];
  float* out = (float*)d_out;
  float* ws  = (float*)d_ws;

  float* h   = ws;                                    // 8192
  unsigned short* e16 = (unsigned short*)(ws + 8192); // 524288 halfs = 262144 f
  float* embT = ws + 8192 + 262144;                   // 524288 (fp32 transpose)
  float* ps  = embT + 524288;                         // 8*16384
  float* pi  = ps + SPLITS * N_PTS;                   // 8*16384
  float* p2  = pi + SPLITS * N_PTS;                   // 8*16384
  int* idxf  = (int*)(p2 + SPLITS * N_PTS);           // 16384
  int* list  = idxf + N_PTS;                          // 16384
  int* cnt   = list + N_PTS;                          // 1
  float* psum = (float*)(cnt + 1);                    // 1024

  float* out_idx  = out + 1048576;
  float* out_loss = out + 1048576 + 16384;

  k_pre<<<32, 256, 0, stream>>>(emb, h, e16, embT, cnt);
  k1_score<<<dim3(64, SPLITS), 256, 0, stream>>>(z, e16, h, ps, pi, p2);
  k2_merge<<<64, 256, 0, stream>>>(ps, pi, p2, idxf, out_idx, list, cnt);
  k_rescue<<<512, 256, 0, stream>>>(z, embT, h, list, cnt, idxf, out_idx);
  k3_quant<<<1024, 256, 0, stream>>>(z, emb, idxf, out, psum);
  k4_loss<<<1, 256, 0, stream>>>(psum, out_loss);
}

// Round 9
// 154.911 us; speedup vs baseline: 1.0591x; 1.0591x over previous
//
#include <hip/hip_runtime.h>

// VQ-VAE vector quantizer. Round 9.
// z: [16,64,32,32] f32, emb: [8192,64] f32. N=16384 pts, C=64, V=8192.
// out = [ z_q_st (1048576) | idx as f32 (16384) | vq_loss (1) ]
//
// R8 post-mortem: k1 latency-bound at 2 waves/SIMD (pt=4 state pushed into
// AGPRs); rescue's c-loop serialized on vmcnt(0) per iter (VALUBusy 12% =
// pure FMA time, 88% stall).
// R9: k1 -> 1024 blocks (4 waves/SIMD), pt=2, med3 top-2 (4 instr/score);
// rescue -> manual prefetch double-buffer (loads for c+1 in flight during
// c's FMAs), unroll 2.

typedef _Float16 half8 __attribute__((ext_vector_type(8)));
typedef float f32x4 __attribute__((ext_vector_type(4)));

#define N_PTS 16384
#define SPLITS 8
#define THR 0.08f

// e16 swizzled (halfs): off(v,c) = (v>>4)*1024 + (c>>5)*512
//                                   + ((c>>3)&3)*128 + (v&15)*8 + (c&7)
// -> per-wave B-frag load (tile T, half H): e16 + T*1024 + H*512 + lane*8,
//    contiguous 1KB, giving B[n=lane&15][k=(lane>>4)*8+j].

// ---------------- k_pre: emb -> swizzled fp16 + fp32 transpose, norms --------
__global__ __launch_bounds__(256) void k_pre(const float* __restrict__ emb,
                                             float* __restrict__ h,
                                             unsigned short* __restrict__ e16,
                                             float* __restrict__ embT,
                                             int* __restrict__ cnt) {
  int v = blockIdx.x * 256 + threadIdx.x;   // grid 32 -> 8192
  const float4* e4 = (const float4*)(emb + v * 64);
  float s = 0.f;
  float row[64];
#pragma unroll
  for (int i = 0; i < 16; ++i) {
    float4 a = e4[i];
    row[i * 4 + 0] = a.x; row[i * 4 + 1] = a.y;
    row[i * 4 + 2] = a.z; row[i * 4 + 3] = a.w;
    s += a.x * a.x + a.y * a.y + a.z * a.z + a.w * a.w;
  }
  unsigned short* base = e16 + (v >> 4) * 1024 + (v & 15) * 8;
#pragma unroll
  for (int c8 = 0; c8 < 8; ++c8) {
    half8 o;
#pragma unroll
    for (int j = 0; j < 8; ++j) o[j] = (_Float16)row[c8 * 8 + j];
    *(half8*)(base + (c8 >> 2) * 512 + (c8 & 3) * 128) = o;
  }
  // fp32 transpose: embT[c][v]; consecutive lanes -> consecutive v: coalesced
#pragma unroll
  for (int c = 0; c < 64; ++c) embT[c * 8192 + v] = row[c];
  h[v] = 0.5f * s;
  if (v == 0) *cnt = 0;
}

// ---------------- k1: 16x16x32 MFMA scores, 2 point-tiles/wave, 4 blk/CU ----
// grid (128, 8). block 256 = 4 waves; wave owns 32 points (2 tiles of 16),
// sweeps 1024 codes (64 tiles). 1024 blocks = 4 blocks/CU = 4 waves/SIMD.
__global__ __launch_bounds__(256, 4) void k1_score(
    const float* __restrict__ z, const unsigned short* __restrict__ e16,
    const float* __restrict__ h,
    float* __restrict__ ps, float* __restrict__ pi, float* __restrict__ p2) {
  const int tid = threadIdx.x;
  const int lane = tid & 63;
  const int wid = tid >> 6;
  const int cl = lane & 15;     // A row (point) / B col (code) within tile
  const int gq = lane >> 4;     // quad: selects k-slice / C rows
  const int n0 = blockIdx.x * 128 + wid * 32;
  const int split = blockIdx.y;

  const int b = n0 >> 10;
  const int hw0 = n0 & 1023;

  // A frags: A[pt][H]  with A[m=cl][k=gq*8+j], half H = channels H*32..+31
  half8 A[2][2];
  {
    const float* zb = z + b * 65536 + hw0 + cl;
#pragma unroll
    for (int pt = 0; pt < 2; ++pt)
#pragma unroll
      for (int H = 0; H < 2; ++H) {
        half8 a;
#pragma unroll
        for (int j = 0; j < 8; ++j)
          a[j] = (_Float16)zb[pt * 16 + (H * 32 + gq * 8 + j) * 1024];
        A[pt][H] = a;
      }
  }

  float s1[2][4], i1f[2][4], s2[2][4];
#pragma unroll
  for (int pt = 0; pt < 2; ++pt)
#pragma unroll
    for (int r = 0; r < 4; ++r) {
      s1[pt][r] = -3.0e38f; i1f[pt][r] = 0.f; s2[pt][r] = -3.0e38f;
    }

  const int vbase = split * 1024;
  const unsigned short* bbase = e16 + vbase * 64 + lane * 8;

#pragma unroll 2
  for (int T = 0; T < 64; ++T) {
    const unsigned short* bp = bbase + T * 1024;
    half8 B0 = *(const half8*)bp;
    half8 B1 = *(const half8*)(bp + 512);
    const int code = vbase + T * 16 + cl;
    const float nhv = -h[code];
    const float vf = (float)code;

#pragma unroll
    for (int pt = 0; pt < 2; ++pt) {
      f32x4 acc;
      acc[0] = nhv; acc[1] = nhv; acc[2] = nhv; acc[3] = nhv;
      acc = __builtin_amdgcn_mfma_f32_16x16x32_f16(A[pt][0], B0, acc, 0, 0, 0);
      acc = __builtin_amdgcn_mfma_f32_16x16x32_f16(A[pt][1], B1, acc, 0, 0, 0);

      // running top-2, 4 instr/score: med3 + cmp + cndmask + max
#pragma unroll
      for (int r = 0; r < 4; ++r) {
        float sc = acc[r];
        s2[pt][r] = __builtin_amdgcn_fmed3f(sc, s1[pt][r], s2[pt][r]);
        bool gt = sc > s1[pt][r];               // strict: first occurrence
        i1f[pt][r] = gt ? vf : i1f[pt][r];
        s1[pt][r] = fmaxf(s1[pt][r], sc);
      }
    }
  }

  // butterfly merge across the 16 cols (lanes with same gq hold same rows)
#pragma unroll
  for (int off = 8; off >= 1; off >>= 1) {
#pragma unroll
    for (int pt = 0; pt < 2; ++pt)
#pragma unroll
      for (int r = 0; r < 4; ++r) {
        float os = __shfl_xor(s1[pt][r], off);
        float oi = __shfl_xor(i1f[pt][r], off);
        float o2 = __shfl_xor(s2[pt][r], off);
        s2[pt][r] = fmaxf(fmaxf(s2[pt][r], o2), fminf(s1[pt][r], os));
        bool gt = os > s1[pt][r];   // exact ties -> margin 0 -> rescue
        i1f[pt][r] = gt ? oi : i1f[pt][r];
        s1[pt][r] = fmaxf(s1[pt][r], os);
      }
  }

  if (cl == 0) {
#pragma unroll
    for (int pt = 0; pt < 2; ++pt)
#pragma unroll
      for (int r = 0; r < 4; ++r) {
        int n = n0 + pt * 16 + gq * 4 + r;     // C row = gq*4 + reg
        int o = split * N_PTS + n;
        ps[o] = s1[pt][r]; pi[o] = i1f[pt][r]; p2[o] = s2[pt][r];
      }
  }
}

// ---------------- k2: merge splits, margin test, emit idx ----------------
__global__ __launch_bounds__(256) void k2_merge(
    const float* __restrict__ ps, const float* __restrict__ pi,
    const float* __restrict__ p2,
    int* __restrict__ idxf, float* __restrict__ out_idx,
    int* __restrict__ list, int* __restrict__ cnt) {
  int n = blockIdx.x * 256 + threadIdx.x;   // grid 64 -> 16384
  float S1 = ps[n], I1 = pi[n], S2 = p2[n];
#pragma unroll
  for (int s = 1; s < SPLITS; ++s) {
    int o = s * N_PTS + n;
    float a = ps[o], ai = pi[o], a2 = p2[o];
    if (a > S1) { S2 = fmaxf(fmaxf(S2, a2), S1); S1 = a; I1 = ai; }
    else        { S2 = fmaxf(S2, a); }
  }
  idxf[n] = (int)I1;
  out_idx[n] = I1;
  if (S1 - S2 < THR) {
    int p = atomicAdd(cnt, 1);
    list[p] = n;
  }
}

// ---------------- k_rescue: exact fp32, 4 points/block, prefetch pipe --------
// Thread t owns 32 codes (8 float4 of embT); 4 points share the sweep.
// Loads for channel c+1 are issued before c's FMAs consume -> latency hidden.
__global__ __launch_bounds__(256, 1) void k_rescue(
    const float* __restrict__ z, const float* __restrict__ embT,
    const float* __restrict__ h, const int* __restrict__ list,
    const int* __restrict__ cnt,
    int* __restrict__ idxf, float* __restrict__ out_idx) {
  __shared__ float zsT[64][4];
  __shared__ int pn[4];
  __shared__ float rs[4][4], ri[4][4];
  const int tid = threadIdx.x;
  const int lane = tid & 63, wv = tid >> 6;
  const int count = *cnt;

  for (int base = blockIdx.x * 4; base < count; base += gridDim.x * 4) {
    const int P = min(4, count - base);
    __syncthreads();
    if (tid < 4) pn[tid] = list[base + min(tid, P - 1)];  // pad with last valid
    __syncthreads();
    {
      int p = tid >> 6, c = tid & 63;
      int n = pn[p];
      zsT[c][p] = z[(n >> 10) * 65536 + c * 1024 + (n & 1023)];
    }
    __syncthreads();

    float d[128];
#pragma unroll
    for (int i = 0; i < 128; ++i) d[i] = 0.f;

    const float4* eT = (const float4*)embT;   // [c][2048] float4 units

    float4 cur[8];
#pragma unroll
    for (int s = 0; s < 8; ++s) cur[s] = eT[s * 256 + tid];

#pragma unroll 2
    for (int c = 0; c < 63; ++c) {
      // prefetch c+1 while computing c
      float4 nxt[8];
      const float4* rowp = eT + (c + 1) * 2048 + tid;
#pragma unroll
      for (int s = 0; s < 8; ++s) nxt[s] = rowp[s * 256];

      float4 zp = *(const float4*)&zsT[c][0];   // broadcast, conflict-free
#pragma unroll
      for (int s = 0; s < 8; ++s) {
        float4 ev = cur[s];
        float* dp = d + s * 16;
        dp[0]  = fmaf(ev.x, zp.x, dp[0]);  dp[1]  = fmaf(ev.x, zp.y, dp[1]);
        dp[2]  = fmaf(ev.x, zp.z, dp[2]);  dp[3]  = fmaf(ev.x, zp.w, dp[3]);
        dp[4]  = fmaf(ev.y, zp.x, dp[4]);  dp[5]  = fmaf(ev.y, zp.y, dp[5]);
        dp[6]  = fmaf(ev.y, zp.z, dp[6]);  dp[7]  = fmaf(ev.y, zp.w, dp[7]);
        dp[8]  = fmaf(ev.z, zp.x, dp[8]);  dp[9]  = fmaf(ev.z, zp.y, dp[9]);
        dp[10] = fmaf(ev.z, zp.z, dp[10]); dp[11] = fmaf(ev.z, zp.w, dp[11]);
        dp[12] = fmaf(ev.w, zp.x, dp[12]); dp[13] = fmaf(ev.w, zp.y, dp[13]);
        dp[14] = fmaf(ev.w, zp.z, dp[14]); dp[15] = fmaf(ev.w, zp.w, dp[15]);
      }
#pragma unroll
      for (int s = 0; s < 8; ++s) cur[s] = nxt[s];
    }
    {
      // peeled last channel
      float4 zp = *(const float4*)&zsT[63][0];
#pragma unroll
      for (int s = 0; s < 8; ++s) {
        float4 ev = cur[s];
        float* dp = d + s * 16;
        dp[0]  = fmaf(ev.x, zp.x, dp[0]);  dp[1]  = fmaf(ev.x, zp.y, dp[1]);
        dp[2]  = fmaf(ev.x, zp.z, dp[2]);  dp[3]  = fmaf(ev.x, zp.w, dp[3]);
        dp[4]  = fmaf(ev.y, zp.x, dp[4]);  dp[5]  = fmaf(ev.y, zp.y, dp[5]);
        dp[6]  = fmaf(ev.y, zp.z, dp[6]);  dp[7]  = fmaf(ev.y, zp.w, dp[7]);
        dp[8]  = fmaf(ev.z, zp.x, dp[8]);  dp[9]  = fmaf(ev.z, zp.y, dp[9]);
        dp[10] = fmaf(ev.z, zp.z, dp[10]); dp[11] = fmaf(ev.z, zp.w, dp[11]);
        dp[12] = fmaf(ev.w, zp.x, dp[12]); dp[13] = fmaf(ev.w, zp.y, dp[13]);
        dp[14] = fmaf(ev.w, zp.z, dp[14]); dp[15] = fmaf(ev.w, zp.w, dp[15]);
      }
    }

    // per-thread argmax per point over its 32 codes (code-ascending, strict >)
    float bs[4], bi[4];
#pragma unroll
    for (int p = 0; p < 4; ++p) { bs[p] = -3.0e38f; bi[p] = 0.f; }
#pragma unroll
    for (int s = 0; s < 8; ++s) {
      float4 hv = *(const float4*)(h + s * 1024 + tid * 4);
#pragma unroll
      for (int k = 0; k < 4; ++k) {
        float hk = (k == 0) ? hv.x : (k == 1) ? hv.y : (k == 2) ? hv.z : hv.w;
        float cf = (float)(s * 1024 + tid * 4 + k);
#pragma unroll
        for (int p = 0; p < 4; ++p) {
          float sc = d[s * 16 + k * 4 + p] - hk;
          if (sc > bs[p]) { bs[p] = sc; bi[p] = cf; }
        }
      }
    }

    // wave butterfly (disjoint code sets; tie -> lower code), then cross-wave
#pragma unroll
    for (int off = 32; off >= 1; off >>= 1) {
#pragma unroll
      for (int p = 0; p < 4; ++p) {
        float os = __shfl_xor(bs[p], off);
        float oi = __shfl_xor(bi[p], off);
        if (os > bs[p] || (os == bs[p] && oi < bi[p])) { bs[p] = os; bi[p] = oi; }
      }
    }
    if (lane == 0)
#pragma unroll
      for (int p = 0; p < 4; ++p) { rs[wv][p] = bs[p]; ri[wv][p] = bi[p]; }
    __syncthreads();
    if (tid < 4) {
      int p = tid;
      float s = rs[0][p], i = ri[0][p];
#pragma unroll
      for (int w = 1; w < 4; ++w) {
        if (rs[w][p] > s || (rs[w][p] == s && ri[w][p] < i)) { s = rs[w][p]; i = ri[w][p]; }
      }
      if (p < P) {
        int n = pn[p];
        idxf[n] = (int)i;
        out_idx[n] = i;
      }
    }
  }
}

// ---------------- k3: gather, straight-through out, block partial loss --------
__global__ __launch_bounds__(256) void k3_quant(
    const float* __restrict__ z, const float* __restrict__ emb,
    const int* __restrict__ idxf,
    float* __restrict__ out, float* __restrict__ psum) {
  int t = blockIdx.x * 256 + threadIdx.x;   // grid 1024 -> 262144 float4 slots
  int g = t * 4;
  int b = g >> 16;
  int c = (g >> 10) & 63;
  int hw = g & 1023;
  int n = (b << 10) | hw;                   // n..n+3, 4-aligned
  float4 zv = *(const float4*)(z + g);
  int4 iv = *(const int4*)(idxf + n);
  float q0 = emb[iv.x * 64 + c];
  float q1 = emb[iv.y * 64 + c];
  float q2 = emb[iv.z * 64 + c];
  float q3 = emb[iv.w * 64 + c];
  float d0 = q0 - zv.x, d1 = q1 - zv.y, d2 = q2 - zv.z, d3 = q3 - zv.w;
  float4 o;
  o.x = zv.x + d0; o.y = zv.y + d1; o.z = zv.z + d2; o.w = zv.w + d3;
  *(float4*)(out + g) = o;
  float val = d0 * d0 + d1 * d1 + d2 * d2 + d3 * d3;
#pragma unroll
  for (int off = 32; off >= 1; off >>= 1) val += __shfl_down(val, off);
  __shared__ float wsum[4];
  int lane = threadIdx.x & 63, wv = threadIdx.x >> 6;
  if (lane == 0) wsum[wv] = val;
  __syncthreads();
  if (threadIdx.x == 0)
    psum[blockIdx.x] = wsum[0] + wsum[1] + wsum[2] + wsum[3];
}

// ---------------- k4: final loss reduce (1024 partials) ----------------
__global__ __launch_bounds__(256) void k4_loss(const float* __restrict__ psum,
                                               float* __restrict__ out_loss) {
  int tid = threadIdx.x;
  float val = psum[tid] + psum[tid + 256] + psum[tid + 512] + psum[tid + 768];
#pragma unroll
  for (int off = 32; off >= 1; off >>= 1) val += __shfl_down(val, off);
  __shared__ float wsum[4];
  int lane = tid & 63, wv = tid >> 6;
  if (lane == 0) wsum[wv] = val;
  __syncthreads();
  if (tid == 0)
    out_loss[0] = 1.25f * (wsum[0] + wsum[1] + wsum[2] + wsum[3]) * (1.0f / 1048576.0f);
}

extern "C" void kernel_launch(void* const* d_in, const int* in_sizes, int n_in,
                              void* d_out, int out_size, void* d_ws, size_t ws_size,
                              hipStream_t stream) {
  const float* z   = (const float*)d_in[0];
  const float* emb = (const float*)d_in[1];
  float* out = (float*)d_out;
  float* ws  = (float*)d_ws;

  float* h   = ws;                                    // 8192
  unsigned short* e16 = (unsigned short*)(ws + 8192); // 524288 halfs = 262144 f
  float* embT = ws + 8192 + 262144;                   // 524288 (fp32 transpose)
  float* ps  = embT + 524288;                         // 8*16384
  float* pi  = ps + SPLITS * N_PTS;                   // 8*16384
  float* p2  = pi + SPLITS * N_PTS;                   // 8*16384
  int* idxf  = (int*)(p2 + SPLITS * N_PTS);           // 16384
  int* list  = idxf + N_PTS;                          // 16384
  int* cnt   = list + N_PTS;                          // 1
  float* psum = (float*)(cnt + 1);                    // 1024

  float* out_idx  = out + 1048576;
  float* out_loss = out + 1048576 + 16384;

  k_pre<<<32, 256, 0, stream>>>(emb, h, e16, embT, cnt);
  k1_score<<<dim3(128, SPLITS), 256, 0, stream>>>(z, e16, h, ps, pi, p2);
  k2_merge<<<64, 256, 0, stream>>>(ps, pi, p2, idxf, out_idx, list, cnt);
  k_rescue<<<512, 256, 0, stream>>>(z, embT, h, list, cnt, idxf, out_idx);
  k3_quant<<<1024, 256, 0, stream>>>(z, emb, idxf, out, psum);
  k4_loss<<<1, 256, 0, stream>>>(psum, out_loss);
}

// Round 10
// 145.200 us; speedup vs baseline: 1.1299x; 1.0669x over previous
//
#include <hip/hip_runtime.h>

// VQ-VAE vector quantizer. Round 10.
// z: [16,64,32,32] f32, emb: [8192,64] f32. N=16384 pts, C=64, V=8192.
// out = [ z_q_st (1048576) | idx as f32 (16384) | vq_loss (1) ]
//
// R9 post-mortem: rescue's prefetch was defeated by VGPR pressure (192 =
// alloc wall; nxt[] folded away -> 8 serialized ~200cyc L2 hits/iter,
// 1600 cyc/iter, VALUBusy 16%). Floor of the shape: 2MB per-block ingest
// through L1 = 13.6us.
// R10: rescue -> 1024 threads, 8 codes/thread, 4 pts/block: d[32]+buf 16
// ~= 80 VGPR, 16 waves/block TLP, 2 loads/iter -> L1-bound ~14-17us.

typedef _Float16 half8 __attribute__((ext_vector_type(8)));
typedef float f32x4 __attribute__((ext_vector_type(4)));

#define N_PTS 16384
#define SPLITS 8
#define THR 0.08f

// e16 swizzled (halfs): per-wave B-frag load (tile T, half H):
// e16 + T*1024 + H*512 + lane*8 -> contiguous 1KB,
// giving B[n=lane&15][k=(lane>>4)*8+j].

// ---------------- k_pre: emb -> swizzled fp16 + fp32 transpose, norms --------
__global__ __launch_bounds__(256) void k_pre(const float* __restrict__ emb,
                                             float* __restrict__ h,
                                             unsigned short* __restrict__ e16,
                                             float* __restrict__ embT,
                                             int* __restrict__ cnt) {
  int v = blockIdx.x * 256 + threadIdx.x;   // grid 32 -> 8192
  const float4* e4 = (const float4*)(emb + v * 64);
  float s = 0.f;
  float row[64];
#pragma unroll
  for (int i = 0; i < 16; ++i) {
    float4 a = e4[i];
    row[i * 4 + 0] = a.x; row[i * 4 + 1] = a.y;
    row[i * 4 + 2] = a.z; row[i * 4 + 3] = a.w;
    s += a.x * a.x + a.y * a.y + a.z * a.z + a.w * a.w;
  }
  unsigned short* base = e16 + (v >> 4) * 1024 + (v & 15) * 8;
#pragma unroll
  for (int c8 = 0; c8 < 8; ++c8) {
    half8 o;
#pragma unroll
    for (int j = 0; j < 8; ++j) o[j] = (_Float16)row[c8 * 8 + j];
    *(half8*)(base + (c8 >> 2) * 512 + (c8 & 3) * 128) = o;
  }
  // fp32 transpose: embT[c][v]; consecutive lanes -> consecutive v: coalesced
#pragma unroll
  for (int c = 0; c < 64; ++c) embT[c * 8192 + v] = row[c];
  h[v] = 0.5f * s;
  if (v == 0) *cnt = 0;
}

// ---------------- k1: 16x16x32 MFMA scores, 2 point-tiles/wave, 4 blk/CU ----
// grid (128, 8). block 256 = 4 waves; wave owns 32 points (2 tiles of 16),
// sweeps 1024 codes (64 tiles). 1024 blocks = 4 blocks/CU = 4 waves/SIMD.
__global__ __launch_bounds__(256, 4) void k1_score(
    const float* __restrict__ z, const unsigned short* __restrict__ e16,
    const float* __restrict__ h,
    float* __restrict__ ps, float* __restrict__ pi, float* __restrict__ p2) {
  const int tid = threadIdx.x;
  const int lane = tid & 63;
  const int wid = tid >> 6;
  const int cl = lane & 15;     // A row (point) / B col (code) within tile
  const int gq = lane >> 4;     // quad: selects k-slice / C rows
  const int n0 = blockIdx.x * 128 + wid * 32;
  const int split = blockIdx.y;

  const int b = n0 >> 10;
  const int hw0 = n0 & 1023;

  // A frags: A[pt][H]  with A[m=cl][k=gq*8+j], half H = channels H*32..+31
  half8 A[2][2];
  {
    const float* zb = z + b * 65536 + hw0 + cl;
#pragma unroll
    for (int pt = 0; pt < 2; ++pt)
#pragma unroll
      for (int H = 0; H < 2; ++H) {
        half8 a;
#pragma unroll
        for (int j = 0; j < 8; ++j)
          a[j] = (_Float16)zb[pt * 16 + (H * 32 + gq * 8 + j) * 1024];
        A[pt][H] = a;
      }
  }

  float s1[2][4], i1f[2][4], s2[2][4];
#pragma unroll
  for (int pt = 0; pt < 2; ++pt)
#pragma unroll
    for (int r = 0; r < 4; ++r) {
      s1[pt][r] = -3.0e38f; i1f[pt][r] = 0.f; s2[pt][r] = -3.0e38f;
    }

  const int vbase = split * 1024;
  const unsigned short* bbase = e16 + vbase * 64 + lane * 8;

#pragma unroll 2
  for (int T = 0; T < 64; ++T) {
    const unsigned short* bp = bbase + T * 1024;
    half8 B0 = *(const half8*)bp;
    half8 B1 = *(const half8*)(bp + 512);
    const int code = vbase + T * 16 + cl;
    const float nhv = -h[code];
    const float vf = (float)code;

#pragma unroll
    for (int pt = 0; pt < 2; ++pt) {
      f32x4 acc;
      acc[0] = nhv; acc[1] = nhv; acc[2] = nhv; acc[3] = nhv;
      acc = __builtin_amdgcn_mfma_f32_16x16x32_f16(A[pt][0], B0, acc, 0, 0, 0);
      acc = __builtin_amdgcn_mfma_f32_16x16x32_f16(A[pt][1], B1, acc, 0, 0, 0);

      // running top-2, 4 instr/score: med3 + cmp + cndmask + max
#pragma unroll
      for (int r = 0; r < 4; ++r) {
        float sc = acc[r];
        s2[pt][r] = __builtin_amdgcn_fmed3f(sc, s1[pt][r], s2[pt][r]);
        bool gt = sc > s1[pt][r];               // strict: first occurrence
        i1f[pt][r] = gt ? vf : i1f[pt][r];
        s1[pt][r] = fmaxf(s1[pt][r], sc);
      }
    }
  }

  // butterfly merge across the 16 cols (lanes with same gq hold same rows)
#pragma unroll
  for (int off = 8; off >= 1; off >>= 1) {
#pragma unroll
    for (int pt = 0; pt < 2; ++pt)
#pragma unroll
      for (int r = 0; r < 4; ++r) {
        float os = __shfl_xor(s1[pt][r], off);
        float oi = __shfl_xor(i1f[pt][r], off);
        float o2 = __shfl_xor(s2[pt][r], off);
        s2[pt][r] = fmaxf(fmaxf(s2[pt][r], o2), fminf(s1[pt][r], os));
        bool gt = os > s1[pt][r];   // exact ties -> margin 0 -> rescue
        i1f[pt][r] = gt ? oi : i1f[pt][r];
        s1[pt][r] = fmaxf(s1[pt][r], os);
      }
  }

  if (cl == 0) {
#pragma unroll
    for (int pt = 0; pt < 2; ++pt)
#pragma unroll
      for (int r = 0; r < 4; ++r) {
        int n = n0 + pt * 16 + gq * 4 + r;     // C row = gq*4 + reg
        int o = split * N_PTS + n;
        ps[o] = s1[pt][r]; pi[o] = i1f[pt][r]; p2[o] = s2[pt][r];
      }
  }
}

// ---------------- k2: merge splits, margin test, emit idx ----------------
__global__ __launch_bounds__(256) void k2_merge(
    const float* __restrict__ ps, const float* __restrict__ pi,
    const float* __restrict__ p2,
    int* __restrict__ idxf, float* __restrict__ out_idx,
    int* __restrict__ list, int* __restrict__ cnt) {
  int n = blockIdx.x * 256 + threadIdx.x;   // grid 64 -> 16384
  float S1 = ps[n], I1 = pi[n], S2 = p2[n];
#pragma unroll
  for (int s = 1; s < SPLITS; ++s) {
    int o = s * N_PTS + n;
    float a = ps[o], ai = pi[o], a2 = p2[o];
    if (a > S1) { S2 = fmaxf(fmaxf(S2, a2), S1); S1 = a; I1 = ai; }
    else        { S2 = fmaxf(S2, a); }
  }
  idxf[n] = (int)I1;
  out_idx[n] = I1;
  if (S1 - S2 < THR) {
    int p = atomicAdd(cnt, 1);
    list[p] = n;
  }
}

// ---------------- k_rescue: exact fp32, 1024 thr, 8 codes/thr, 4 pts/blk ----
// Thread t owns codes {4t..4t+3, 4096+4t..4096+4t+3} (2 float4 of embT/c).
// d[8 codes][4 pts] = 32 accs; ~80 VGPR -> 16 waves/block resident (4/SIMD),
// 2 loads/iter prefetched. No cross-lane ops in the hot loop.
__global__ __launch_bounds__(1024, 4) void k_rescue(
    const float* __restrict__ z, const float* __restrict__ embT,
    const float* __restrict__ h, const int* __restrict__ list,
    const int* __restrict__ cnt,
    int* __restrict__ idxf, float* __restrict__ out_idx) {
  __shared__ float zsT[64][4];
  __shared__ int pn[4];
  __shared__ float rs[16][4], ri[16][4];
  const int tid = threadIdx.x;
  const int lane = tid & 63, wv = tid >> 6;
  const int count = *cnt;

  for (int base = blockIdx.x * 4; base < count; base += gridDim.x * 4) {
    const int P = min(4, count - base);
    __syncthreads();
    if (tid < 4) pn[tid] = list[base + min(tid, P - 1)];  // pad with last valid
    __syncthreads();
    if (tid < 256) {
      int p = tid >> 6, c = tid & 63;
      int n = pn[p];
      zsT[c][p] = z[(n >> 10) * 65536 + c * 1024 + (n & 1023)];
    }
    __syncthreads();

    float d[32];
#pragma unroll
    for (int i = 0; i < 32; ++i) d[i] = 0.f;

    const float4* eT = (const float4*)embT;   // rows of 2048 float4
    float4 cur0 = eT[tid];                    // c=0, codes 4t..4t+3
    float4 cur1 = eT[1024 + tid];             // c=0, codes 4096+4t..+3

    for (int c = 0; c < 64; ++c) {
      float4 nxt0, nxt1;
      if (c < 63) {
        const float4* rowp = eT + (c + 1) * 2048 + tid;
        nxt0 = rowp[0];
        nxt1 = rowp[1024];
      }
      float4 zp = *(const float4*)&zsT[c][0];   // broadcast, conflict-free
      float ev[8] = {cur0.x, cur0.y, cur0.z, cur0.w,
                     cur1.x, cur1.y, cur1.z, cur1.w};
#pragma unroll
      for (int k = 0; k < 8; ++k) {
        d[k * 4 + 0] = fmaf(ev[k], zp.x, d[k * 4 + 0]);
        d[k * 4 + 1] = fmaf(ev[k], zp.y, d[k * 4 + 1]);
        d[k * 4 + 2] = fmaf(ev[k], zp.z, d[k * 4 + 2]);
        d[k * 4 + 3] = fmaf(ev[k], zp.w, d[k * 4 + 3]);
      }
      if (c < 63) { cur0 = nxt0; cur1 = nxt1; }
    }

    // per-thread argmax per point over its 8 codes (code-ascending, strict >)
    float4 hv0 = *(const float4*)(h + tid * 4);
    float4 hv1 = *(const float4*)(h + 4096 + tid * 4);
    float bs[4], bi[4];
#pragma unroll
    for (int p = 0; p < 4; ++p) { bs[p] = -3.0e38f; bi[p] = 0.f; }
#pragma unroll
    for (int k = 0; k < 8; ++k) {
      float hk = (k == 0) ? hv0.x : (k == 1) ? hv0.y : (k == 2) ? hv0.z :
                 (k == 3) ? hv0.w : (k == 4) ? hv1.x : (k == 5) ? hv1.y :
                 (k == 6) ? hv1.z : hv1.w;
      float cf = (float)((k < 4 ? 0 : 4096) + tid * 4 + (k & 3));
#pragma unroll
      for (int p = 0; p < 4; ++p) {
        float sc = d[k * 4 + p] - hk;
        if (sc > bs[p]) { bs[p] = sc; bi[p] = cf; }
      }
    }

    // wave butterfly (disjoint code sets; tie -> lower code), then cross-wave
#pragma unroll
    for (int off = 32; off >= 1; off >>= 1) {
#pragma unroll
      for (int p = 0; p < 4; ++p) {
        float os = __shfl_xor(bs[p], off);
        float oi = __shfl_xor(bi[p], off);
        if (os > bs[p] || (os == bs[p] && oi < bi[p])) { bs[p] = os; bi[p] = oi; }
      }
    }
    if (lane == 0)
#pragma unroll
      for (int p = 0; p < 4; ++p) { rs[wv][p] = bs[p]; ri[wv][p] = bi[p]; }
    __syncthreads();
    if (tid < 4) {
      int p = tid;
      float s = rs[0][p], i = ri[0][p];
#pragma unroll
      for (int w = 1; w < 16; ++w) {
        if (rs[w][p] > s || (rs[w][p] == s && ri[w][p] < i)) { s = rs[w][p]; i = ri[w][p]; }
      }
      if (p < P) {
        int n = pn[p];
        idxf[n] = (int)i;
        out_idx[n] = i;
      }
    }
  }
}

// ---------------- k3: gather, straight-through out, block partial loss --------
__global__ __launch_bounds__(256) void k3_quant(
    const float* __restrict__ z, const float* __restrict__ emb,
    const int* __restrict__ idxf,
    float* __restrict__ out, float* __restrict__ psum) {
  int t = blockIdx.x * 256 + threadIdx.x;   // grid 1024 -> 262144 float4 slots
  int g = t * 4;
  int b = g >> 16;
  int c = (g >> 10) & 63;
  int hw = g & 1023;
  int n = (b << 10) | hw;                   // n..n+3, 4-aligned
  float4 zv = *(const float4*)(z + g);
  int4 iv = *(const int4*)(idxf + n);
  float q0 = emb[iv.x * 64 + c];
  float q1 = emb[iv.y * 64 + c];
  float q2 = emb[iv.z * 64 + c];
  float q3 = emb[iv.w * 64 + c];
  float d0 = q0 - zv.x, d1 = q1 - zv.y, d2 = q2 - zv.z, d3 = q3 - zv.w;
  float4 o;
  o.x = zv.x + d0; o.y = zv.y + d1; o.z = zv.z + d2; o.w = zv.w + d3;
  *(float4*)(out + g) = o;
  float val = d0 * d0 + d1 * d1 + d2 * d2 + d3 * d3;
#pragma unroll
  for (int off = 32; off >= 1; off >>= 1) val += __shfl_down(val, off);
  __shared__ float wsum[4];
  int lane = threadIdx.x & 63, wv = threadIdx.x >> 6;
  if (lane == 0) wsum[wv] = val;
  __syncthreads();
  if (threadIdx.x == 0)
    psum[blockIdx.x] = wsum[0] + wsum[1] + wsum[2] + wsum[3];
}

// ---------------- k4: final loss reduce (1024 partials) ----------------
__global__ __launch_bounds__(256) void k4_loss(const float* __restrict__ psum,
                                               float* __restrict__ out_loss) {
  int tid = threadIdx.x;
  float val = psum[tid] + psum[tid + 256] + psum[tid + 512] + psum[tid + 768];
#pragma unroll
  for (int off = 32; off >= 1; off >>= 1) val += __shfl_down(val, off);
  __shared__ float wsum[4];
  int lane = tid & 63, wv = tid >> 6;
  if (lane == 0) wsum[wv] = val;
  __syncthreads();
  if (tid == 0)
    out_loss[0] = 1.25f * (wsum[0] + wsum[1] + wsum[2] + wsum[3]) * (1.0f / 1048576.0f);
}

extern "C" void kernel_launch(void* const* d_in, const int* in_sizes, int n_in,
                              void* d_out, int out_size, void* d_ws, size_t ws_size,
                              hipStream_t stream) {
  const float* z   = (const float*)d_in[0];
  const float* emb = (const float*)d_in[1];
  float* out = (float*)d_out;
  float* ws  = (float*)d_ws;

  float* h   = ws;                                    // 8192
  unsigned short* e16 = (unsigned short*)(ws + 8192); // 524288 halfs = 262144 f
  float* embT = ws + 8192 + 262144;                   // 524288 (fp32 transpose)
  float* ps  = embT + 524288;                         // 8*16384
  float* pi  = ps + SPLITS * N_PTS;                   // 8*16384
  float* p2  = pi + SPLITS * N_PTS;                   // 8*16384
  int* idxf  = (int*)(p2 + SPLITS * N_PTS);           // 16384
  int* list  = idxf + N_PTS;                          // 16384
  int* cnt   = list + N_PTS;                          // 1
  float* psum = (float*)(cnt + 1);                    // 1024

  float* out_idx  = out + 1048576;
  float* out_loss = out + 1048576 + 16384;

  k_pre<<<32, 256, 0, stream>>>(emb, h, e16, embT, cnt);
  k1_score<<<dim3(128, SPLITS), 256, 0, stream>>>(z, e16, h, ps, pi, p2);
  k2_merge<<<64, 256, 0, stream>>>(ps, pi, p2, idxf, out_idx, list, cnt);
  k_rescue<<<256, 1024, 0, stream>>>(z, embT, h, list, cnt, idxf, out_idx);
  k3_quant<<<1024, 256, 0, stream>>>(z, emb, idxf, out, psum);
  k4_loss<<<1, 256, 0, stream>>>(psum, out_loss);
}